// Round 8
// baseline (990.181 us; speedup 1.0000x reference)
//
#include <hip/hip_runtime.h>

// MultilayeredNetwork v6: bucket-sort + LDS fixed-point accumulation.
// Key insight (R7 post-mortem): determinism comes from ORDER-INDEPENDENT int64
// fixed-point sums, so NO stable sort is needed — only bucket grouping so a
// block can hold its rows' accumulators in LDS.
//   build: bcount (782-bin hist, LDS+bulk atomics) -> bscan -> passA (cursor scatter)
//   per t: block = 128-row bucket; stream slab edges, gather state, LDS i64 atomics;
//          epilogue: convert -> tanh -> inject -> plane[t][n][b]
//   final: planes[t][n][b] -> out[b][n][t]
// Fixed-point scale 2^44: fp32 mult exact (exp shift), int64 sum exact ->
// bitwise-identical replays regardless of slab order / atomic timing.

#define N_NEURONS 100000
#define NNZ_CNT   3200000
#define N_SENSORY 5000
#define BATCH     16
#define T_LAYERS  8
#define THRESH    0.01f
#define STEEP     5.0f

#define NB (N_NEURONS * BATCH)
#define NT (N_NEURONS * T_LAYERS)
#define ST (N_SENSORY * T_LAYERS)

#define FXSCALE   17592186044416.0f        /* 2^44 */
#define FXINV     (1.0 / 17592186044416.0) /* double, exact */

#define LBITS   7
#define BROWS   (1 << LBITS)                           /* 128 rows per bucket */
#define NBUCKET ((N_NEURONS + BROWS - 1) / BROWS)      /* 782 */
#define EPB     8192                                   /* edges per build block */
#define NBLK_A  ((NNZ_CNT + EPB - 1) / EPB)            /* 391 */

__device__ __forceinline__ float thresh_clamp_inp(float u) {
    u = (u >= THRESH) ? u : 0.0f;
    return fminf(u, 1.0f);
}
__device__ __forceinline__ float activate(float y) {
    y = (y >= THRESH) ? y : 0.0f;
    return tanhf(STEEP * y);
}

// ---------------- build ----------------

// state0 (planes[7] slot) + zero bucket totals.
__global__ void k_init(const float* __restrict__ inp, float* __restrict__ state0,
                       int* __restrict__ btotal) {
    int i = blockIdx.x * blockDim.x + threadIdx.x;
    if (i >= NB) return;
    int n = i >> 4, b = i & 15;
    float v = 0.0f;
    if (n < N_SENSORY) v = thresh_clamp_inp(inp[b * ST + n * T_LAYERS + 0]);
    state0[i] = v;
    if (i < NBUCKET) btotal[i] = 0;
}

// 782-bin bucket histogram: LDS count per block, one global atomic per (bucket, block).
__global__ void __launch_bounds__(1024) k_bcount(const int* __restrict__ rows,
                                                 int* __restrict__ btotal) {
    __shared__ int cnt[NBUCKET];
    const int e0 = blockIdx.x * EPB;
    for (int i = threadIdx.x; i < NBUCKET; i += 1024) cnt[i] = 0;
    __syncthreads();
    #pragma unroll
    for (int i = 0; i < EPB / 1024; ++i) {
        int e = e0 + i * 1024 + threadIdx.x;
        if (e < NNZ_CNT) atomicAdd(&cnt[rows[e] >> LBITS], 1);
    }
    __syncthreads();
    for (int i = threadIdx.x; i < NBUCKET; i += 1024)
        if (cnt[i]) atomicAdd(&btotal[i], cnt[i]);
}

// single-block exclusive scan of 782 bucket totals -> bbase, bcur.
__global__ void __launch_bounds__(1024) k_bscan(const int* __restrict__ btotal,
                                                int* __restrict__ bbase,
                                                int* __restrict__ bcur) {
    __shared__ int lds[1024];
    int tid = threadIdx.x;
    int v = (tid < NBUCKET) ? btotal[tid] : 0;
    lds[tid] = v;
    __syncthreads();
    for (int off = 1; off < 1024; off <<= 1) {
        int add = (tid >= off) ? lds[tid - off] : 0;
        __syncthreads();
        lds[tid] += add;
        __syncthreads();
    }
    if (tid < NBUCKET) {
        bbase[tid] = lds[tid] - v;
        bcur[tid]  = lds[tid] - v;
    }
    if (tid == 0) bbase[NBUCKET] = NNZ_CNT;
}

// two-level scatter into bucket slabs (order within bucket: arbitrary — harmless).
// lo word packs (col << 7) | (row & 127); hi word = val bits.
__global__ void __launch_bounds__(1024) k_passA(const float* __restrict__ vals,
                                                const int* __restrict__ rows,
                                                const int* __restrict__ cols,
                                                int* bcur,
                                                int2* __restrict__ slab) {
    __shared__ int cnt[NBUCKET];
    __shared__ int base[NBUCKET];
    const int e0 = blockIdx.x * EPB;
    for (int i = threadIdx.x; i < NBUCKET; i += 1024) cnt[i] = 0;
    __syncthreads();
    #pragma unroll
    for (int i = 0; i < EPB / 1024; ++i) {
        int e = e0 + i * 1024 + threadIdx.x;
        if (e < NNZ_CNT) atomicAdd(&cnt[rows[e] >> LBITS], 1);
    }
    __syncthreads();
    for (int i = threadIdx.x; i < NBUCKET; i += 1024) {
        int c = cnt[i];
        base[i] = (c > 0) ? atomicAdd(&bcur[i], c) : 0;
        cnt[i] = 0;
    }
    __syncthreads();
    #pragma unroll
    for (int i = 0; i < EPB / 1024; ++i) {
        int e = e0 + i * 1024 + threadIdx.x;
        if (e < NNZ_CNT) {
            int r = rows[e];
            int k = r >> LBITS;
            int pos = base[k] + atomicAdd(&cnt[k], 1);
            slab[pos] = make_int2((cols[e] << LBITS) | (r & (BROWS - 1)),
                                  __float_as_int(vals[e]));
        }
    }
}

// ---------------- per-layer: bucket-local LDS fixed-point SpMM + activation ----------------
// Block = one 128-row bucket. 16 groups x 16 lanes; group streams 16 edges
// (coalesced 128B load + shfl broadcast), lane b handles batch b.
__global__ void __launch_bounds__(256) k_layer(const int* __restrict__ bbase,
                                               const int2* __restrict__ slab,
                                               const float* __restrict__ state_in,
                                               const float* __restrict__ inp,
                                               float* __restrict__ plane_out,
                                               int t) {
    __shared__ unsigned long long acc[BROWS * BATCH];   // 16 KB
    const int tid = threadIdx.x;
    const int k = blockIdx.x;
    const int r0 = k * BROWS;
    for (int i = tid; i < BROWS * BATCH; i += 256) acc[i] = 0ull;
    __syncthreads();
    const int P0 = bbase[k], P1 = bbase[k + 1];
    const int g = tid >> 4, b = tid & 15;
    for (int base = P0 + g * 16; base < P1; base += 256) {
        int idx = base + b;
        int2 pe = (idx < P1) ? slab[idx] : make_int2(0, 0);   // val=0 pad: no-op
        #pragma unroll
        for (int j = 0; j < 16; ++j) {
            int   lo = __shfl(pe.x, j, 16);
            float v  = __int_as_float(__shfl(pe.y, j, 16));
            int   c  = lo >> LBITS;
            int   lr = lo & (BROWS - 1);
            float prod = v * state_in[c * BATCH + b];          // coalesced 64B gather
            if (prod != 0.0f) {                                // ~half of xv are exactly 0
                long long fx = llrintf(prod * FXSCALE);
                atomicAdd(&acc[lr * BATCH + b], (unsigned long long)fx);
            }
        }
    }
    __syncthreads();
    // epilogue: convert, activate, inject, write plane (contiguous 8 KB)
    const int rend = min(BROWS, N_NEURONS - r0);
    for (int i = tid; i < rend * BATCH; i += 256) {
        int lr = i >> 4, bb = i & 15;
        float y = (float)((double)(long long)acc[i] * FXINV);
        float a = activate(y);
        int r = r0 + lr;
        if (t < T_LAYERS - 1) {
            if (r < N_SENSORY) a += thresh_clamp_inp(inp[bb * ST + r * T_LAYERS + (t + 1)]);
            a = fminf(a, 1.0f);                                // off-sensory no-op (|tanh|<1)
        }
        plane_out[r * BATCH + bb] = a;
    }
}

// ---------------- planes[t][n][b] -> out[b][n][t] ----------------
__global__ void k_out(const float* __restrict__ planes, float* __restrict__ out) {
    int i = blockIdx.x * blockDim.x + threadIdx.x;
    if (i >= NB) return;
    int n = i >> 4, b = i & 15;
    float4 o0, o1;
    o0.x = planes[0 * NB + i]; o0.y = planes[1 * NB + i];
    o0.z = planes[2 * NB + i]; o0.w = planes[3 * NB + i];
    o1.x = planes[4 * NB + i]; o1.y = planes[5 * NB + i];
    o1.z = planes[6 * NB + i]; o1.w = planes[7 * NB + i];
    float4* dst = (float4*)&out[b * NT + n * T_LAYERS];
    dst[0] = o0; dst[1] = o1;
}

// ---------------- fallback (atomic fixed-point path, 19.2 MB ws) ----------------
__global__ void k2_init(const float* __restrict__ inp, float* __restrict__ state,
                        long long* __restrict__ acc) {
    int stride = gridDim.x * blockDim.x;
    for (int i = blockIdx.x * blockDim.x + threadIdx.x; i < NB; i += stride) {
        int n = i >> 4, b = i & 15;
        float v = 0.0f;
        if (n < N_SENSORY) v = thresh_clamp_inp(inp[b * ST + n * T_LAYERS + 0]);
        state[i] = v;
        acc[i]   = 0LL;
    }
}
__global__ void __launch_bounds__(256) k2_spmm(const float* __restrict__ vals,
                                               const int* __restrict__ rows,
                                               const int* __restrict__ cols,
                                               const float* __restrict__ state,
                                               long long* acc) {
    int tid = blockIdx.x * blockDim.x + threadIdx.x;
    int b = tid & 15;
    int e = tid >> 4;
    int estride = (gridDim.x * blockDim.x) >> 4;
    for (; e < NNZ_CNT; e += estride) {
        float xv = state[cols[e] * BATCH + b];
        long long fx = llrintf(vals[e] * xv * FXSCALE);
        if (fx != 0LL)
            atomicAdd((unsigned long long*)&acc[rows[e] * BATCH + b], (unsigned long long)fx);
    }
}
__global__ void k2_act_inject(long long* acc, const float* __restrict__ inp,
                              float* __restrict__ state, float* __restrict__ out, int t) {
    int stride = gridDim.x * blockDim.x;
    for (int i = blockIdx.x * blockDim.x + threadIdx.x; i < NB; i += stride) {
        int n = i >> 4, b = i & 15;
        float y = (float)((double)acc[i] * FXINV);
        acc[i] = 0LL;
        float v = activate(y);
        if (n < N_SENSORY) v += thresh_clamp_inp(inp[b * ST + n * T_LAYERS + (t + 1)]);
        v = fminf(v, 1.0f);
        state[i] = v;
        out[b * NT + n * T_LAYERS + t] = v;
    }
}
__global__ void k2_act_final(const long long* __restrict__ acc, float* __restrict__ out) {
    int stride = gridDim.x * blockDim.x;
    for (int i = blockIdx.x * blockDim.x + threadIdx.x; i < NB; i += stride) {
        int n = i >> 4, b = i & 15;
        float y = (float)((double)acc[i] * FXINV);
        out[b * NT + n * T_LAYERS + (T_LAYERS - 1)] = activate(y);
    }
}

extern "C" void kernel_launch(void* const* d_in, const int* in_sizes, int n_in,
                              void* d_out, int out_size, void* d_ws, size_t ws_size,
                              hipStream_t stream) {
    const float* inputs = (const float*)d_in[0];
    const float* vals   = (const float*)d_in[1];
    const int*   rows   = (const int*)  d_in[2];
    const int*   cols   = (const int*)  d_in[3];
    float* out = (float*)d_out;

    const size_t sz_planes = (size_t)T_LAYERS * NB * 4;   // 51.2 MB
    const size_t sz_slab   = (size_t)NNZ_CNT * 8;         // 25.6 MB (persists through layers)
    const size_t sz_bt     = (size_t)(NBUCKET + 8) * 4;
    const size_t REQ = sz_planes + sz_slab + 3 * sz_bt;

    const int block = 256;

    if (ws_size >= REQ) {
        char* ws = (char*)d_ws;
        float* planes = (float*)ws;
        int2*  slab   = (int2*)(ws + sz_planes);
        int*   btotal = (int*)(ws + sz_planes + sz_slab);
        int*   bbase  = (int*)(ws + sz_planes + sz_slab + sz_bt);
        int*   bcur   = (int*)(ws + sz_planes + sz_slab + 2 * sz_bt);
        float* state0 = planes + (size_t)(T_LAYERS - 1) * NB;  // planes[7], consumed by t=0

        const int grid_nb = (NB + block - 1) / block;          // 6250

        k_init<<<grid_nb, block, 0, stream>>>(inputs, state0, btotal);
        k_bcount<<<NBLK_A, 1024, 0, stream>>>(rows, btotal);
        k_bscan<<<1, 1024, 0, stream>>>(btotal, bbase, bcur);
        k_passA<<<NBLK_A, 1024, 0, stream>>>(vals, rows, cols, bcur, slab);

        for (int t = 0; t < T_LAYERS; ++t) {
            const float* sin_ = (t == 0) ? state0 : planes + (size_t)(t - 1) * NB;
            k_layer<<<NBUCKET, block, 0, stream>>>(bbase, slab, sin_, inputs,
                                                   planes + (size_t)t * NB, t);
        }
        k_out<<<grid_nb, block, 0, stream>>>(planes, out);
    } else {
        long long* acc   = (long long*)d_ws;
        float*     state = (float*)(acc + NB);
        const int grid_ew = 2048, grid_sp = 2048;
        k2_init<<<grid_ew, block, 0, stream>>>(inputs, state, acc);
        for (int t = 0; t < T_LAYERS; ++t) {
            k2_spmm<<<grid_sp, block, 0, stream>>>(vals, rows, cols, state, acc);
            if (t < T_LAYERS - 1)
                k2_act_inject<<<grid_ew, block, 0, stream>>>(acc, inputs, state, out, t);
            else
                k2_act_final<<<grid_ew, block, 0, stream>>>(acc, out);
        }
    }
}

// Round 10
// 400.792 us; speedup vs baseline: 2.4706x; 2.4706x over previous
//
#include <hip/hip_runtime.h>

// MultilayeredNetwork v8 = v7 structure with UNBIASED int32 fixed point.
// R9 failed (absmax 0.086): (int)prod truncation is a BIASED quantizer (2^-25,
// toward zero); ~66-term sums accumulated 1-4e-6 systematic error -> threshold
// flips amplified by the recurrence. Fix: __float2int_rn (unbiased, rndne) at
// scale 2^27. Prescale val*2^27 is exact; fl(vs*x) = fl(v*x)*2^27 exactly, so
// per-term error <= 2^-28 unbiased (rms ~1e-8, below R7's passing level).
// Overflow: |running sum| <= Sum|v| ~ 6 max << 16 = 2^31/2^27. int32 sums are
// order-independent -> bitwise-identical graph replays despite cursor scatter.
//   build: bcount (196-bin hist) -> bscan -> passA (two-level cursor scatter,
//          PRESCALED vals) -> passB (per-bucket LDS hist+scan -> row_ptr + CSR)
//   per t: 16-lane group per row; LDS edge broadcast; int32-rn accumulate.
//   final: planes[t][n][b] -> out[b][n][t]

#define N_NEURONS 100000
#define NNZ_CNT   3200000
#define N_SENSORY 5000
#define BATCH     16
#define T_LAYERS  8
#define THRESH    0.01f
#define STEEP     5.0f

#define NB (N_NEURONS * BATCH)
#define NT (N_NEURONS * T_LAYERS)
#define ST (N_SENSORY * T_LAYERS)

#define FXS32     134217728.0f             /* 2^27: exact fp32 prescale */
#define FXI32     7.450580596923828e-9f    /* 2^-27 exact */

#define LBITS   9
#define BROWS   (1 << LBITS)                           /* 512 rows per bucket */
#define NBUCKET ((N_NEURONS + BROWS - 1) / BROWS)      /* 196 */
#define EPB     4096                                   /* edges per build block */
#define NBLK_A  ((NNZ_CNT + EPB - 1) / EPB)            /* 782 */

#define FXSCALE   17592186044416.0f        /* fallback path only (2^44) */
#define FXINV     (1.0 / 17592186044416.0)

__device__ __forceinline__ float thresh_clamp_inp(float u) {
    u = (u >= THRESH) ? u : 0.0f;
    return fminf(u, 1.0f);
}
__device__ __forceinline__ float activate(float y) {
    y = (y >= THRESH) ? y : 0.0f;
    return tanhf(STEEP * y);
}

// ---------------- build ----------------

// state0 (planes[7] slot) + zero bucket totals.
__global__ void k_init(const float* __restrict__ inp, float* __restrict__ state0,
                       int* __restrict__ btotal) {
    int i = blockIdx.x * blockDim.x + threadIdx.x;
    if (i >= NB) return;
    int n = i >> 4, b = i & 15;
    float v = 0.0f;
    if (n < N_SENSORY) v = thresh_clamp_inp(inp[b * ST + n * T_LAYERS + 0]);
    state0[i] = v;
    if (i < NBUCKET) btotal[i] = 0;
}

// 196-bin bucket histogram: LDS count per block, one global atomic per (bucket, block).
__global__ void __launch_bounds__(1024) k_bcount(const int* __restrict__ rows,
                                                 int* __restrict__ btotal) {
    __shared__ int cnt[NBUCKET];
    const int e0 = blockIdx.x * EPB;
    for (int i = threadIdx.x; i < NBUCKET; i += 1024) cnt[i] = 0;
    __syncthreads();
    #pragma unroll
    for (int i = 0; i < EPB / 1024; ++i) {
        int e = e0 + i * 1024 + threadIdx.x;
        if (e < NNZ_CNT) atomicAdd(&cnt[rows[e] >> LBITS], 1);
    }
    __syncthreads();
    for (int i = threadIdx.x; i < NBUCKET; i += 1024)
        if (cnt[i]) atomicAdd(&btotal[i], cnt[i]);
}

// single-block exclusive scan of 196 bucket totals -> bbase, bcur.
__global__ void k_bscan(const int* __restrict__ btotal, int* __restrict__ bbase,
                        int* __restrict__ bcur, int* __restrict__ row_ptr) {
    __shared__ int lds[256];
    int tid = threadIdx.x;
    int v = (tid < NBUCKET) ? btotal[tid] : 0;
    lds[tid] = v;
    __syncthreads();
    for (int off = 1; off < 256; off <<= 1) {
        int add = (tid >= off) ? lds[tid - off] : 0;
        __syncthreads();
        lds[tid] += add;
        __syncthreads();
    }
    if (tid < NBUCKET) {
        bbase[tid] = lds[tid] - v;
        bcur[tid]  = lds[tid] - v;
    }
    if (tid == 0) { bbase[NBUCKET] = NNZ_CNT; row_ptr[N_NEURONS] = NNZ_CNT; }
}

// pass A: two-level scatter into bucket slabs. Block bins EPB edges in LDS,
// bulk-reserves slab space (ONE global atomic per bucket per block), places edges.
// lo word packs (col << 9) | (row & 511); hi word = PRESCALED (2^27) val bits.
__global__ void __launch_bounds__(1024) k_passA(const float* __restrict__ vals,
                                                const int* __restrict__ rows,
                                                const int* __restrict__ cols,
                                                int* bcur,
                                                int2* __restrict__ slab) {
    __shared__ int cnt[NBUCKET];
    __shared__ int base[NBUCKET];
    const int e0 = blockIdx.x * EPB;
    for (int i = threadIdx.x; i < NBUCKET; i += 1024) cnt[i] = 0;
    __syncthreads();
    #pragma unroll
    for (int i = 0; i < EPB / 1024; ++i) {
        int e = e0 + i * 1024 + threadIdx.x;
        if (e < NNZ_CNT) atomicAdd(&cnt[rows[e] >> LBITS], 1);
    }
    __syncthreads();
    for (int i = threadIdx.x; i < NBUCKET; i += 1024) {
        int c = cnt[i];
        base[i] = (c > 0) ? atomicAdd(&bcur[i], c) : 0;
        cnt[i] = 0;
    }
    __syncthreads();
    #pragma unroll
    for (int i = 0; i < EPB / 1024; ++i) {
        int e = e0 + i * 1024 + threadIdx.x;
        if (e < NNZ_CNT) {
            int r = rows[e];
            int k = r >> LBITS;
            int pos = base[k] + atomicAdd(&cnt[k], 1);
            slab[pos] = make_int2((cols[e] << LBITS) | (r & (BROWS - 1)),
                                  __float_as_int(vals[e] * FXS32));   // exact prescale
        }
    }
}

// pass B: per-bucket slab -> LDS row histogram + scan -> row_ptr AND final CSR scatter.
__global__ void __launch_bounds__(1024) k_passB(const int* __restrict__ bbase,
                                                const int2* __restrict__ slab,
                                                int2* __restrict__ packed,
                                                int* __restrict__ row_ptr) {
    __shared__ int cnt[BROWS];
    __shared__ int scn[BROWS];
    const int tid = threadIdx.x;
    const int k  = blockIdx.x;
    const int r0 = k * BROWS;
    const int nr = min(BROWS, N_NEURONS - r0);
    const int P0 = bbase[k], P1 = bbase[k + 1];
    for (int i = tid; i < BROWS; i += 1024) cnt[i] = 0;
    __syncthreads();
    for (int i = P0 + tid; i < P1; i += 1024)
        atomicAdd(&cnt[slab[i].x & (BROWS - 1)], 1);
    __syncthreads();
    if (tid < BROWS) scn[tid] = cnt[tid];
    __syncthreads();
    for (int off = 1; off < BROWS; off <<= 1) {
        int add = (tid < BROWS && tid >= off) ? scn[tid - off] : 0;
        __syncthreads();
        if (tid < BROWS) scn[tid] += add;
        __syncthreads();
    }
    if (tid < BROWS) {
        int ex = P0 + scn[tid] - cnt[tid];      // exclusive row base
        if (tid < nr) row_ptr[r0 + tid] = ex;
        scn[tid] = ex;                          // cursor
    }
    __syncthreads();
    for (int i = P0 + tid; i < P1; i += 1024) {
        int2 pe = slab[i];
        int d = atomicAdd(&scn[pe.x & (BROWS - 1)], 1);
        packed[d] = make_int2(pe.x >> LBITS, pe.y);   // (col, prescaled val)
    }
}

// ---------------- fused per-layer SpMM + activation ----------------
// 16-lane group per row (lane = batch). Edge broadcast via LDS (1 ds_write_b64 +
// 16 same-address ds_read_b64) — group is within one wave: no barrier.
// int32 round-to-nearest fixed-point register accumulation (vals prescaled 2^27).
__global__ void __launch_bounds__(256) k_layer(const int* __restrict__ row_ptr,
                                               const int2* __restrict__ packed,
                                               const float* __restrict__ state_in,
                                               const float* __restrict__ inp,
                                               float* __restrict__ plane_out,
                                               int t) {
    __shared__ int2 ebuf[16][17];               // [group][slot], +1 pad
    const int tid = threadIdx.x;
    const int g = tid >> 4, b = tid & 15;
    const int r = blockIdx.x * 16 + g;          // 6250*16 == N_NEURONS exactly
    const int s = row_ptr[r], e = row_ptr[r + 1];
    int acc = 0;
    for (int base = s; base < e; base += 16) {
        int idx = base + b;
        int2 pe = (idx < e) ? packed[idx] : make_int2(0, 0);   // val=0 pad: exact no-op
        ebuf[g][b] = pe;                        // wave-lockstep, in-order DS pipe
        #pragma unroll
        for (int j = 0; j < 16; ++j) {
            int2 q = ebuf[g][j];                // 16-lane same-address broadcast read
            float prod = __int_as_float(q.y) * state_in[q.x * BATCH + b];
            acc += __float2int_rn(prod);        // UNBIASED quantization at 2^-28
        }
    }
    float y = (float)acc * FXI32;
    float a = activate(y);
    if (t < T_LAYERS - 1) {
        if (r < N_SENSORY) a += thresh_clamp_inp(inp[b * ST + r * T_LAYERS + (t + 1)]);
        a = fminf(a, 1.0f);                     // off-sensory no-op (|tanh|<1)
    }
    plane_out[r * BATCH + b] = a;
}

// ---------------- planes[t][n][b] -> out[b][n][t] ----------------
__global__ void k_out(const float* __restrict__ planes, float* __restrict__ out) {
    int i = blockIdx.x * blockDim.x + threadIdx.x;
    if (i >= NB) return;
    int n = i >> 4, b = i & 15;
    float4 o0, o1;
    o0.x = planes[0 * NB + i]; o0.y = planes[1 * NB + i];
    o0.z = planes[2 * NB + i]; o0.w = planes[3 * NB + i];
    o1.x = planes[4 * NB + i]; o1.y = planes[5 * NB + i];
    o1.z = planes[6 * NB + i]; o1.w = planes[7 * NB + i];
    float4* dst = (float4*)&out[b * NT + n * T_LAYERS];
    dst[0] = o0; dst[1] = o1;
}

// ---------------- fallback (atomic fixed-point path, 19.2 MB ws) ----------------
__global__ void k2_init(const float* __restrict__ inp, float* __restrict__ state,
                        long long* __restrict__ acc) {
    int stride = gridDim.x * blockDim.x;
    for (int i = blockIdx.x * blockDim.x + threadIdx.x; i < NB; i += stride) {
        int n = i >> 4, b = i & 15;
        float v = 0.0f;
        if (n < N_SENSORY) v = thresh_clamp_inp(inp[b * ST + n * T_LAYERS + 0]);
        state[i] = v;
        acc[i]   = 0LL;
    }
}
__global__ void __launch_bounds__(256) k2_spmm(const float* __restrict__ vals,
                                               const int* __restrict__ rows,
                                               const int* __restrict__ cols,
                                               const float* __restrict__ state,
                                               long long* acc) {
    int tid = blockIdx.x * blockDim.x + threadIdx.x;
    int b = tid & 15;
    int e = tid >> 4;
    int estride = (gridDim.x * blockDim.x) >> 4;
    for (; e < NNZ_CNT; e += estride) {
        float xv = state[cols[e] * BATCH + b];
        long long fx = llrintf(vals[e] * xv * FXSCALE);
        if (fx != 0LL)
            atomicAdd((unsigned long long*)&acc[rows[e] * BATCH + b], (unsigned long long)fx);
    }
}
__global__ void k2_act_inject(long long* acc, const float* __restrict__ inp,
                              float* __restrict__ state, float* __restrict__ out, int t) {
    int stride = gridDim.x * blockDim.x;
    for (int i = blockIdx.x * blockDim.x + threadIdx.x; i < NB; i += stride) {
        int n = i >> 4, b = i & 15;
        float y = (float)((double)acc[i] * FXINV);
        acc[i] = 0LL;
        float v = activate(y);
        if (n < N_SENSORY) v += thresh_clamp_inp(inp[b * ST + n * T_LAYERS + (t + 1)]);
        v = fminf(v, 1.0f);
        state[i] = v;
        out[b * NT + n * T_LAYERS + t] = v;
    }
}
__global__ void k2_act_final(const long long* __restrict__ acc, float* __restrict__ out) {
    int stride = gridDim.x * blockDim.x;
    for (int i = blockIdx.x * blockDim.x + threadIdx.x; i < NB; i += stride) {
        int n = i >> 4, b = i & 15;
        float y = (float)((double)acc[i] * FXINV);
        out[b * NT + n * T_LAYERS + (T_LAYERS - 1)] = activate(y);
    }
}

extern "C" void kernel_launch(void* const* d_in, const int* in_sizes, int n_in,
                              void* d_out, int out_size, void* d_ws, size_t ws_size,
                              hipStream_t stream) {
    const float* inputs = (const float*)d_in[0];
    const float* vals   = (const float*)d_in[1];
    const int*   rows   = (const int*)  d_in[2];
    const int*   cols   = (const int*)  d_in[3];
    float* out = (float*)d_out;

    const size_t sz_planes = (size_t)T_LAYERS * NB * 4;   // 51.2 MB
    const size_t sz_packed = (size_t)NNZ_CNT * 8;         // 25.6 MB
    const size_t sz_rowptr = ((size_t)N_NEURONS + 2) * 4;
    const size_t sz_bt     = (size_t)(NBUCKET + 8) * 4;
    const size_t REQ = sz_planes + sz_packed + sz_rowptr + 3 * sz_bt;

    const int block = 256;

    if (ws_size >= REQ) {
        char* ws = (char*)d_ws;
        float* planes  = (float*)ws;
        int2*  packed  = (int2*)(ws + sz_planes);
        int*   row_ptr = (int*)(ws + sz_planes + sz_packed);
        int*   btotal  = (int*)(ws + sz_planes + sz_packed + sz_rowptr);
        int*   bbase   = (int*)(ws + sz_planes + sz_packed + sz_rowptr + sz_bt);
        int*   bcur    = (int*)(ws + sz_planes + sz_packed + sz_rowptr + 2 * sz_bt);
        float* state0  = planes + (size_t)(T_LAYERS - 1) * NB;  // planes[7], consumed at t=0
        int2*  slab    = (int2*)planes;   // build scratch aliases planes[0..3]; dead before layers

        const int grid_nb = (NB + block - 1) / block;           // 6250

        k_init<<<grid_nb, block, 0, stream>>>(inputs, state0, btotal);
        k_bcount<<<NBLK_A, 1024, 0, stream>>>(rows, btotal);
        k_bscan<<<1, 256, 0, stream>>>(btotal, bbase, bcur, row_ptr);
        k_passA<<<NBLK_A, 1024, 0, stream>>>(vals, rows, cols, bcur, slab);
        k_passB<<<NBUCKET, 1024, 0, stream>>>(bbase, slab, packed, row_ptr);

        for (int t = 0; t < T_LAYERS; ++t) {
            const float* sin_ = (t == 0) ? state0 : planes + (size_t)(t - 1) * NB;
            k_layer<<<grid_nb, block, 0, stream>>>(row_ptr, packed, sin_, inputs,
                                                   planes + (size_t)t * NB, t);
        }
        k_out<<<grid_nb, block, 0, stream>>>(planes, out);
    } else {
        long long* acc   = (long long*)d_ws;
        float*     state = (float*)(acc + NB);
        const int grid_ew = 2048, grid_sp = 2048;
        k2_init<<<grid_ew, block, 0, stream>>>(inputs, state, acc);
        for (int t = 0; t < T_LAYERS; ++t) {
            k2_spmm<<<grid_sp, block, 0, stream>>>(vals, rows, cols, state, acc);
            if (t < T_LAYERS - 1)
                k2_act_inject<<<grid_ew, block, 0, stream>>>(acc, inputs, state, out, t);
            else
                k2_act_final<<<grid_ew, block, 0, stream>>>(acc, out);
        }
    }
}